// Round 1
// baseline (4065.953 us; speedup 1.0000x reference)
//
#include <hip/hip_runtime.h>

// out[b,c] = H @ x[b,c] @ H^T for 65536 independent 32x32 fp32 tiles.
// Memory-bound (512 MiB traffic, 8.6 GFLOP). One wave per tile; 4 waves/block;
// 4 tiles per wave with register prefetch. No in-loop __syncthreads (per-wave
// LDS buffers). H stored transposed in LDS -> broadcast, conflict-free reads
// in both stages.

typedef float float4v __attribute__((ext_vector_type(4)));

#define PAD 36  // 144 B row stride: 16B-aligned for ds_read_b128, breaks pow2 banks

__global__ __launch_bounds__(256, 4) void dct32_kernel(
    const float* __restrict__ x, const float* __restrict__ Hm,
    float* __restrict__ out) {
  __shared__ float Hs[32 * 32];       // Hs[k][l] = H[l][k]  (H transposed)
  __shared__ float Xs[4][32 * PAD];   // per-wave X tile (padded rows)
  __shared__ float Ts[4][32 * PAD];   // per-wave intermediate T = X*Ht

  const int tid  = threadIdx.x;
  const int wave = tid >> 6;
  const int lane = tid & 63;
  const int jb = lane >> 3;   // 0..7  row-block
  const int lb = lane & 7;    // 0..7  col-block
  const int j0 = jb << 2;
  const int l0 = lb << 2;

  // Stage H transposed into LDS (once per block).
  for (int i = tid; i < 1024; i += 256) {
    int r = i >> 5, c = i & 31;
    Hs[c * 32 + r] = Hm[i];
  }
  __syncthreads();

  float* __restrict__ xs = Xs[wave];
  float* __restrict__ ts = Ts[wave];

  const float4v* __restrict__ xv = (const float4v*)x;
  float4v* __restrict__ ov = (float4v*)out;

  // tiles: this wave handles tileBase + it*4, it = 0..3 (adjacent waves ->
  // adjacent tiles at the same instant, contiguous 16 KB per block access).
  const int tileBase = blockIdx.x * 16 + wave;

  // Prologue: load tile 0 into registers (coalesced float4, nontemporal).
  float4v xr[4];
  {
    const float4v* p = xv + (size_t)tileBase * 256 + lane;
#pragma unroll
    for (int r = 0; r < 4; ++r) xr[r] = __builtin_nontemporal_load(p + r * 64);
  }

  for (int it = 0; it < 4; ++it) {
    // Write staged tile to LDS. flat idx = r*256 + lane*4 -> row r*8+jb, col l0.
#pragma unroll
    for (int r = 0; r < 4; ++r)
      *(float4v*)&xs[(r * 8 + jb) * PAD + l0] = xr[r];

    // Prefetch next tile into the same registers (hides HBM latency under
    // the two matmul stages below).
    if (it < 3) {
      const float4v* p = xv + (size_t)(tileBase + (it + 1) * 4) * 256 + lane;
#pragma unroll
      for (int r = 0; r < 4; ++r) xr[r] = __builtin_nontemporal_load(p + r * 64);
    }

    // ---- Stage 1: T[j][l] = sum_k X[j][k] * H[l][k]  (lane block 4x4) ----
    float acc[4][4] = {};
#pragma unroll
    for (int k0 = 0; k0 < 32; k0 += 4) {
      float4v xf[4], hf[4];
#pragma unroll
      for (int jj = 0; jj < 4; ++jj)
        xf[jj] = *(const float4v*)&xs[(j0 + jj) * PAD + k0];
#pragma unroll
      for (int kk = 0; kk < 4; ++kk)
        hf[kk] = *(const float4v*)&Hs[(k0 + kk) * 32 + l0];  // Ht[k][l0:4]
#pragma unroll
      for (int jj = 0; jj < 4; ++jj)
#pragma unroll
        for (int kk = 0; kk < 4; ++kk)
#pragma unroll
          for (int ll = 0; ll < 4; ++ll)
            acc[jj][ll] = fmaf(xf[jj][kk], hf[kk][ll], acc[jj][ll]);
    }
#pragma unroll
    for (int jj = 0; jj < 4; ++jj)
      *(float4v*)&ts[(j0 + jj) * PAD + l0] = *(const float4v*)&acc[jj][0];

    // ---- Stage 2: Y[i][l] = sum_j Ht[j][i] * T[j][l]  (i0 = j0) ----
    float acc2[4][4] = {};
#pragma unroll
    for (int jg = 0; jg < 32; jg += 4) {
      float4v hf[4], tf[4];
#pragma unroll
      for (int jj = 0; jj < 4; ++jj)
        hf[jj] = *(const float4v*)&Hs[(jg + jj) * 32 + j0];  // Ht[j][i0:4]
#pragma unroll
      for (int jj = 0; jj < 4; ++jj)
        tf[jj] = *(const float4v*)&ts[(jg + jj) * PAD + l0];
#pragma unroll
      for (int jj = 0; jj < 4; ++jj)
#pragma unroll
        for (int ii = 0; ii < 4; ++ii)
#pragma unroll
          for (int ll = 0; ll < 4; ++ll)
            acc2[ii][ll] = fmaf(hf[jj][ii], tf[jj][ll], acc2[ii][ll]);
    }

    // ---- Store Y rows i0..i0+3, cols l0..l0+3 (coalesced float4) ----
    float4v* po = ov + (size_t)(tileBase + it * 4) * 256;
#pragma unroll
    for (int ii = 0; ii < 4; ++ii)
      __builtin_nontemporal_store(*(const float4v*)&acc2[ii][0],
                                  po + (j0 + ii) * 8 + lb);
  }
}

extern "C" void kernel_launch(void* const* d_in, const int* in_sizes, int n_in,
                              void* d_out, int out_size, void* d_ws, size_t ws_size,
                              hipStream_t stream) {
  const float* x  = (const float*)d_in[0];
  const float* Hm = (const float*)d_in[1];
  float* out = (float*)d_out;

  const int ntiles = in_sizes[0] / 1024;   // 65536
  const int blocks = ntiles / 16;          // 16 tiles per block (4 per wave)
  dct32_kernel<<<blocks, 256, 0, stream>>>(x, Hm, out);
}

// Round 3
// 462.008 us; speedup vs baseline: 8.8006x; 8.8006x over previous
//
#include <hip/hip_runtime.h>
#include <stdint.h>

// out[b,c] = H @ x[b,c] @ H^T, 65536 independent 32x32 fp32 tiles.
// Memory-bound: 512 MiB traffic (85 us floor @6.3TB/s), 8.6 GFLOP (55 us VALU floor).
// One wave per tile stream (4 tiles/wave), per-wave double-buffered LDS X tile
// filled by async global_load_lds (no VGPR staging, no __syncthreads in loop),
// counted vmcnt waits. X stored source-pre-swizzled (col4 ^= row>>2) so the
// stage-1 column-slice ds_read_b128s are bank-conflict-free; T overwrites the
// X buffer in place (row-uniform reads -> conflict-free unpadded).

typedef float float4v __attribute__((ext_vector_type(4)));

__device__ __forceinline__ void gload_lds16(const float* g, float* l) {
  __builtin_amdgcn_global_load_lds(
      (const __attribute__((address_space(1))) uint32_t*)g,
      (__attribute__((address_space(3))) uint32_t*)l, 16, 0, 0);
}

__global__ __launch_bounds__(256) void dct32_kernel(
    const float* __restrict__ x, const float* __restrict__ Hm,
    float* __restrict__ out) {
  __shared__ float Hs[1024];        // Hs[k][l] = H[l][k]  (H transposed)
  __shared__ float Xb[4][2][1024];  // per-wave double-buffered X tile (linear)

  const int tid  = threadIdx.x;
  const int wave = tid >> 6;
  const int lane = tid & 63;
  const int jb = lane >> 3, lb = lane & 7;   // 8x8 lane grid
  const int j0 = jb << 2,   l0 = lb << 2;    // 4x4 output block per lane

  // Stage H^T into LDS once per block (reads coalesced; one-time cost).
  for (int i = tid; i < 1024; i += 256) Hs[(i & 31) * 32 + (i >> 5)] = Hm[i];
  __syncthreads();

  float* const bufs[2] = {Xb[wave][0], Xb[wave][1]};

  // Per-lane pre-swizzled global float4-slot for DMA instr r:
  // linear LDS slot f = r*64+lane -> row=f>>3, col4'=f&7; source col4 = col4'^ (row>>2)
  int gslot[4];
#pragma unroll
  for (int r = 0; r < 4; ++r) {
    const int f = r * 64 + lane, row = f >> 3;
    gslot[r] = row * 8 + ((f & 7) ^ (row >> 2));
  }

  const int tile0 = blockIdx.x * 16 + wave;  // this wave: tiles tile0 + 4*it
  float4v* const ov = (float4v*)out;

  // Prologue: async-stage tile0 into buf0.
#pragma unroll
  for (int r = 0; r < 4; ++r)
    gload_lds16(x + (size_t)tile0 * 1024 + gslot[r] * 4, bufs[0] + r * 256);

#pragma unroll
  for (int it = 0; it < 4; ++it) {
    float* const cur = bufs[it & 1];

    // Issue next tile's DMA before computing current (stays in flight across
    // the compute; counted vmcnt below never drains it).
    if (it < 3) {
      float* const nxt = bufs[(it + 1) & 1];
      const size_t tn = (size_t)(tile0 + (it + 1) * 4) * 1024;
#pragma unroll
      for (int r = 0; r < 4; ++r)
        gload_lds16(x + tn + gslot[r] * 4, nxt + r * 256);
    }
    // Outstanding VMEM (oldest first):
    //  it=0: [cur DMA 4][next DMA 4]            -> vmcnt(4) drains cur
    //  it=1,2: [cur DMA 4][stores 4][next DMA 4]-> vmcnt(8) drains cur
    //  it=3: [cur DMA 4][stores 4]              -> vmcnt(4) drains cur
    if (it == 0 || it == 3) asm volatile("s_waitcnt vmcnt(4)" ::: "memory");
    else                    asm volatile("s_waitcnt vmcnt(8)" ::: "memory");

    // ---- Stage 1: T[j][l] = sum_k X[j][k]*H[l][k], lane block rows j0..+3 ----
    float4v acc[4];
#pragma unroll
    for (int jj = 0; jj < 4; ++jj) acc[jj] = 0.0f;
#pragma unroll
    for (int k0 = 0; k0 < 32; k0 += 4) {
      const int xs_off = (((k0 >> 2) ^ jb) << 2);  // swizzled col4 -> float off
      float4v hf[4], xf[4];
#pragma unroll
      for (int kk = 0; kk < 4; ++kk)
        hf[kk] = *(const float4v*)&Hs[(k0 + kk) * 32 + l0];     // broadcast, CF
#pragma unroll
      for (int jj = 0; jj < 4; ++jj)
        xf[jj] = *(const float4v*)&cur[(j0 + jj) * 32 + xs_off]; // swizzled, CF
#pragma unroll
      for (int jj = 0; jj < 4; ++jj)
#pragma unroll
        for (int kk = 0; kk < 4; ++kk)
          acc[jj] += xf[jj][kk] * hf[kk];
    }
    // Write T in place (X rows j0..j0+3 are dead; wave-lockstep makes this safe).
    // T stored UNswizzled: its reads are row-uniform -> conflict-free.
#pragma unroll
    for (int jj = 0; jj < 4; ++jj)
      *(float4v*)&cur[(j0 + jj) * 32 + l0] = acc[jj];

    // ---- Stage 2: out[i][l] = sum_j H[i][j]*T[j][l], i0 = j0 ----
    float4v acc2[4];
#pragma unroll
    for (int ii = 0; ii < 4; ++ii) acc2[ii] = 0.0f;
#pragma unroll
    for (int jg = 0; jg < 32; jg += 4) {
      float4v hf2[4], tf[4];
#pragma unroll
      for (int jj = 0; jj < 4; ++jj)
        hf2[jj] = *(const float4v*)&Hs[(jg + jj) * 32 + j0];    // broadcast, CF
#pragma unroll
      for (int jj = 0; jj < 4; ++jj)
        tf[jj] = *(const float4v*)&cur[(jg + jj) * 32 + l0];    // row-uniform, CF
#pragma unroll
      for (int jj = 0; jj < 4; ++jj)
#pragma unroll
        for (int ii = 0; ii < 4; ++ii)
          acc2[ii] += hf2[jj][ii] * tf[jj];
    }

    // ---- Store 4x4 block (8-lane groups write contiguous 128 B lines) ----
    float4v* const po = ov + (size_t)(tile0 + it * 4) * 256;
#pragma unroll
    for (int ii = 0; ii < 4; ++ii)
      __builtin_nontemporal_store(acc2[ii], po + (j0 + ii) * 8 + lb);
  }
}

extern "C" void kernel_launch(void* const* d_in, const int* in_sizes, int n_in,
                              void* d_out, int out_size, void* d_ws, size_t ws_size,
                              hipStream_t stream) {
  const float* x  = (const float*)d_in[0];
  const float* Hm = (const float*)d_in[1];
  float* out = (float*)d_out;

  const int ntiles = in_sizes[0] / 1024;   // 65536
  const int blocks = ntiles / 16;          // 16 tiles/block (4 per wave)
  dct32_kernel<<<blocks, 256, 0, stream>>>(x, Hm, out);
}